// Round 2
// baseline (377.162 us; speedup 1.0000x reference)
//
#include <hip/hip_runtime.h>
#include <hip/hip_bf16.h>

#define NB 32
#define DIN 512
#define TT 4096
#define DH 500
#define DHP 512
#define EPSV 1e-12f
#define BM 32
#define LDA 520  // bf16 elements; 1040B row stride => conflict-free b128 r/w

typedef short short8 __attribute__((ext_vector_type(8)));
typedef float f32x16 __attribute__((ext_vector_type(16)));
typedef float f32x4 __attribute__((ext_vector_type(4)));

__device__ inline unsigned short f2bf(float f) {
    unsigned int u = __builtin_bit_cast(unsigned int, f);
    unsigned int r = (u + 0x7fffu + ((u >> 16) & 1u)) >> 16;
    return (unsigned short)r;
}

// Kernel 0: convert/pad w1 -> bf16 [512][512], w2 -> f32 [512]
__global__ void prep_kernel(const float* __restrict__ w1, const float* __restrict__ w2,
                            unsigned short* __restrict__ w1b, float* __restrict__ w2f) {
    int idx = blockIdx.x * blockDim.x + threadIdx.x;
    if (idx < DHP * DIN) {
        int h = idx >> 9;
        int d = idx & 511;
        float v = (h < DH) ? w1[h * DIN + d] : 0.f;
        w1b[idx] = f2bf(v);
        if (idx < DHP) w2f[idx] = (idx < DH) ? w2[idx] : 0.f;
    }
}

// Kernel 1: scores[b][t] = sum_h w2[h]*relu(sum_d x[b,d,t]*w1[h,d])
// Block: 8 waves, one 32-t tile. A-operand = w1 (m=h), B-operand = x^T tile
// (n=t) -> D cols (lane&31) = t, rows = h: relu*w2 reduce is in-lane.
__launch_bounds__(512, 8)
__global__ void scores_kernel(const float* __restrict__ x,
                              const unsigned short* __restrict__ w1b,
                              const float* __restrict__ w2f,
                              float* __restrict__ scores) {
    __shared__ unsigned short A_lds[BM][LDA];
    __shared__ float score_lds[BM];

    const int tid = threadIdx.x;
    const int b = blockIdx.x >> 7;             // 128 t-tiles per batch
    const int t0 = (blockIdx.x & 127) * BM;

    if (tid < BM) score_lds[tid] = 0.f;

    // ---- Stage x[b, :, t0..t0+31] -> A_lds[t][d] (bf16), transpose ----
    {
        const int t = tid & 31;
        const int dg = tid >> 4;               // wait: 512 threads / 32 t = 16 d-groups
        // (recompute below properly)
    }
    {
        const int t = tid & 31;
        const int dg = tid >> 5;               // 0..15, each covers 32 d
        const float* xb = x + (size_t)b * DIN * TT + t0 + t;
        #pragma unroll
        for (int oct = 0; oct < 4; ++oct) {
            short8 pk;
            #pragma unroll
            for (int j = 0; j < 8; ++j) {
                float v = xb[(size_t)(dg * 32 + oct * 8 + j) * TT];
                pk[j] = (short)f2bf(v);
            }
            *reinterpret_cast<short8*>(&A_lds[t][dg * 32 + oct * 8]) = pk;
        }
    }
    __syncthreads();

    const int w = tid >> 6;                    // 0..7: h-panel of 64
    const int lane31 = tid & 31;
    const int khalf = (tid >> 5) & 1;

    float s = 0.f;
    #pragma unroll
    for (int hb = 0; hb < 2; ++hb) {
        const int hrow0 = w * 64 + hb * 32;
        const unsigned short* Bp = w1b + (size_t)(hrow0 + lane31) * DIN + khalf * 8;
        const unsigned short* Ap = &A_lds[lane31][khalf * 8];
        f32x16 acc;
        #pragma unroll
        for (int g = 0; g < 16; ++g) acc[g] = 0.f;
        #pragma unroll 8
        for (int ks = 0; ks < 32; ++ks) {
            short8 af = *reinterpret_cast<const short8*>(Bp + ks * 16);
            short8 bf = *reinterpret_cast<const short8*>(Ap + ks * 16);
            acc = __builtin_amdgcn_mfma_f32_32x32x16_bf16(af, bf, acc, 0, 0, 0);
        }
        #pragma unroll
        for (int g = 0; g < 16; ++g) {
            int hrow = hrow0 + (g & 3) + 8 * (g >> 2) + 4 * khalf;
            s += fmaxf(acc[g], 0.f) * w2f[hrow];
        }
    }
    // combine the two khalf partial row-sets, then one atomic per t per wave
    s += __shfl_xor(s, 32, 64);
    if (khalf == 0) atomicAdd(&score_lds[lane31], s);
    __syncthreads();
    if (tid < BM) scores[(size_t)b * TT + t0 + tid] = score_lds[tid];
}

// Kernel 2: softmax over T per batch
__global__ void softmax_kernel(const float* __restrict__ scores, float* __restrict__ attn) {
    __shared__ float red[8];
    const int b = blockIdx.x;
    const int tid = threadIdx.x;
    const float* srow = scores + (size_t)b * TT;
    float v[16];
    float mx = -1e30f;
    #pragma unroll
    for (int j = 0; j < 16; ++j) { v[j] = srow[tid + 256 * j]; mx = fmaxf(mx, v[j]); }
    #pragma unroll
    for (int m = 1; m <= 32; m <<= 1) mx = fmaxf(mx, __shfl_xor(mx, m, 64));
    if ((tid & 63) == 0) red[tid >> 6] = mx;
    __syncthreads();
    mx = fmaxf(fmaxf(red[0], red[1]), fmaxf(red[2], red[3]));
    float sum = 0.f;
    #pragma unroll
    for (int j = 0; j < 16; ++j) { v[j] = __expf(v[j] - mx); sum += v[j]; }
    #pragma unroll
    for (int m = 1; m <= 32; m <<= 1) sum += __shfl_xor(sum, m, 64);
    if ((tid & 63) == 0) red[4 + (tid >> 6)] = sum;
    __syncthreads();
    sum = red[4] + red[5] + red[6] + red[7];
    const float inv = 1.f / sum;
    float* arow = attn + (size_t)b * TT;
    #pragma unroll
    for (int j = 0; j < 16; ++j) arow[tid + 256 * j] = v[j] * inv;
}

// Kernel 3: per (b,d): mean = sum_t x*attn; var = E[x^2]-2*mean*E[x]+mean^2
__global__ void stats_kernel(const float* __restrict__ x, const float* __restrict__ attn,
                             float* __restrict__ out) {
    const int w = threadIdx.x >> 6;
    const int lane = threadIdx.x & 63;
    const int row = blockIdx.x * 4 + w;      // b*512 + d
    const int b = row >> 9;
    const int d = row & 511;
    const float* xr = x + (size_t)row * TT;
    const float* ar = attn + (size_t)b * TT;
    float sx = 0.f, sx2 = 0.f, sxw = 0.f;
    #pragma unroll 4
    for (int i = 0; i < 16; ++i) {
        int t = (i * 64 + lane) * 4;
        f32x4 xv = *reinterpret_cast<const f32x4*>(xr + t);
        f32x4 av = *reinterpret_cast<const f32x4*>(ar + t);
        #pragma unroll
        for (int j = 0; j < 4; ++j) {
            float xx = xv[j];
            sx += xx; sx2 += xx * xx; sxw += xx * av[j];
        }
    }
    #pragma unroll
    for (int m = 1; m <= 32; m <<= 1) {
        sx  += __shfl_xor(sx, m, 64);
        sx2 += __shfl_xor(sx2, m, 64);
        sxw += __shfl_xor(sxw, m, 64);
    }
    if (lane == 0) {
        const float mean = sxw;
        const float ex = sx * (1.f / TT);
        const float ex2 = sx2 * (1.f / TT);
        float var = ex2 - 2.f * mean * ex + mean * mean;
        if (var <= EPSV) var = EPSV;
        out[(size_t)b * 1024 + d] = mean;
        out[(size_t)b * 1024 + 512 + d] = sqrtf(var);
    }
}

extern "C" void kernel_launch(void* const* d_in, const int* in_sizes, int n_in,
                              void* d_out, int out_size, void* d_ws, size_t ws_size,
                              hipStream_t stream) {
    const float* x  = (const float*)d_in[0];
    const float* w1 = (const float*)d_in[1];
    const float* w2 = (const float*)d_in[2];
    float* out = (float*)d_out;

    char* ws = (char*)d_ws;
    unsigned short* w1b = (unsigned short*)ws;                    // 512*512*2 = 512 KB
    float* w2f   = (float*)(ws + DHP * DIN * 2);                  // 2 KB
    float* scores = (float*)(ws + DHP * DIN * 2 + 2048);          // 512 KB
    float* attn   = scores + NB * TT;                             // 512 KB

    prep_kernel<<<(DHP * DIN + 255) / 256, 256, 0, stream>>>(w1, w2, w1b, w2f);
    scores_kernel<<<NB * (TT / BM), 512, 0, stream>>>(x, w1b, w2f, scores);
    softmax_kernel<<<NB, 256, 0, stream>>>(scores, attn);
    stats_kernel<<<NB * DIN / 4, 256, 0, stream>>>(x, attn, out);
}

// Round 3
// 193.789 us; speedup vs baseline: 1.9462x; 1.9462x over previous
//
#include <hip/hip_runtime.h>
#include <hip/hip_bf16.h>

#define NB 32
#define DIN 512
#define TT 4096
#define DH 500
#define DHP 512
#define EPSV 1e-12f
#define BM 64
#define LDA 520  // bf16 elements; 1040B row stride, 16B-aligned rows

typedef short short8 __attribute__((ext_vector_type(8)));
typedef float f32x16 __attribute__((ext_vector_type(16)));
typedef float f32x4 __attribute__((ext_vector_type(4)));

__device__ inline unsigned short f2bf(float f) {
    unsigned int u = __builtin_bit_cast(unsigned int, f);
    unsigned int r = (u + 0x7fffu + ((u >> 16) & 1u)) >> 16;
    return (unsigned short)r;
}

// Kernel 0: convert/pad w1 -> bf16 [512][512], w2 -> f32 [512]
__global__ void prep_kernel(const float* __restrict__ w1, const float* __restrict__ w2,
                            unsigned short* __restrict__ w1b, float* __restrict__ w2f) {
    int idx = blockIdx.x * blockDim.x + threadIdx.x;
    if (idx < DHP * DIN) {
        int h = idx >> 9;
        int d = idx & 511;
        float v = (h < DH) ? w1[h * DIN + d] : 0.f;
        w1b[idx] = f2bf(v);
        if (idx < DHP) w2f[idx] = (idx < DH) ? w2[idx] : 0.f;
    }
}

// Kernel 1: scores[b][t] = sum_h w2[h]*relu(sum_d x[b,d,t]*w1[h,d])
// Block: 8 waves, 64-t tile, all 512 h. Wave w owns h-panel [64w,64w+64)
// (2 MFMA h-tiles) x 2 t-tiles -> 4 f32x16 accumulators. A-operand = w1
// (m=h), B-operand = x^T tile (n=t): D cols (lane&31)=t, rows=h, so the
// relu*w2 reduction over h is in-lane.
__launch_bounds__(512, 4)
__global__ void scores_kernel(const float* __restrict__ x,
                              const unsigned short* __restrict__ w1b,
                              const float* __restrict__ w2f,
                              float* __restrict__ scores) {
    __shared__ unsigned short A_lds[BM][LDA];
    __shared__ float score_lds[BM];

    const int tid = threadIdx.x;
    const int b = blockIdx.x >> 6;             // TT/BM = 64 t-tiles per batch
    const int t0 = (blockIdx.x & 63) * BM;

    if (tid < BM) score_lds[tid] = 0.f;

    // ---- Stage x[b, :, t0..t0+63] -> A_lds[t][d] (bf16) ----
    // 64 lanes cover 64 consecutive t (256B coalesced); 8 d-groups of 64.
    {
        const int ts = tid & 63;
        const int dg = tid >> 6;               // 0..7
        const float* xb = x + (size_t)b * DIN * TT + t0 + ts;
        #pragma unroll
        for (int oct = 0; oct < 8; ++oct) {
            const int d0 = dg * 64 + oct * 8;
            short8 pk;
            #pragma unroll
            for (int j = 0; j < 8; ++j)
                pk[j] = (short)f2bf(xb[(size_t)(d0 + j) * TT]);
            *reinterpret_cast<short8*>(&A_lds[ts][d0]) = pk;
        }
    }
    __syncthreads();

    const int w = tid >> 6;                    // wave id: h-panel of 64
    const int lane31 = tid & 31;
    const int khalf = (tid >> 5) & 1;
    const int hrow0 = w * 64;

    f32x16 acc00, acc01, acc10, acc11;
    #pragma unroll
    for (int g = 0; g < 16; ++g) { acc00[g] = 0.f; acc01[g] = 0.f; acc10[g] = 0.f; acc11[g] = 0.f; }

    const unsigned short* Ap0 = w1b + (size_t)(hrow0 + lane31) * DIN + khalf * 8;
    const unsigned short* Ap1 = Ap0 + 32 * DIN;
    const unsigned short* Bp0 = &A_lds[lane31][khalf * 8];
    const unsigned short* Bp1 = &A_lds[32 + lane31][khalf * 8];

    #pragma unroll 4
    for (int ks = 0; ks < 32; ++ks) {
        const int k0 = ks * 16;
        short8 a0 = *reinterpret_cast<const short8*>(Ap0 + k0);
        short8 a1 = *reinterpret_cast<const short8*>(Ap1 + k0);
        short8 b0 = *reinterpret_cast<const short8*>(Bp0 + k0);
        short8 b1 = *reinterpret_cast<const short8*>(Bp1 + k0);
        acc00 = __builtin_amdgcn_mfma_f32_32x32x16_bf16(a0, b0, acc00, 0, 0, 0);
        acc01 = __builtin_amdgcn_mfma_f32_32x32x16_bf16(a0, b1, acc01, 0, 0, 0);
        acc10 = __builtin_amdgcn_mfma_f32_32x32x16_bf16(a1, b0, acc10, 0, 0, 0);
        acc11 = __builtin_amdgcn_mfma_f32_32x32x16_bf16(a1, b1, acc11, 0, 0, 0);
    }

    // ---- in-lane reduce over h, then combine khalf halves ----
    float s0 = 0.f, s1 = 0.f;
    #pragma unroll
    for (int g = 0; g < 16; ++g) {
        const int rp = (g & 3) + 8 * (g >> 2) + 4 * khalf;
        const float w20 = w2f[hrow0 + rp];
        const float w21 = w2f[hrow0 + 32 + rp];
        s0 += fmaxf(acc00[g], 0.f) * w20 + fmaxf(acc10[g], 0.f) * w21;
        s1 += fmaxf(acc01[g], 0.f) * w20 + fmaxf(acc11[g], 0.f) * w21;
    }
    s0 += __shfl_xor(s0, 32, 64);
    s1 += __shfl_xor(s1, 32, 64);
    if (khalf == 0) {
        atomicAdd(&score_lds[lane31], s0);
        atomicAdd(&score_lds[32 + lane31], s1);
    }
    __syncthreads();
    if (tid < BM) scores[(size_t)b * TT + t0 + tid] = score_lds[tid];
}

// Kernel 2: softmax over T per batch
__global__ void softmax_kernel(const float* __restrict__ scores, float* __restrict__ attn) {
    __shared__ float red[8];
    const int b = blockIdx.x;
    const int tid = threadIdx.x;
    const float* srow = scores + (size_t)b * TT;
    float v[16];
    float mx = -1e30f;
    #pragma unroll
    for (int j = 0; j < 16; ++j) { v[j] = srow[tid + 256 * j]; mx = fmaxf(mx, v[j]); }
    #pragma unroll
    for (int m = 1; m <= 32; m <<= 1) mx = fmaxf(mx, __shfl_xor(mx, m, 64));
    if ((tid & 63) == 0) red[tid >> 6] = mx;
    __syncthreads();
    mx = fmaxf(fmaxf(red[0], red[1]), fmaxf(red[2], red[3]));
    float sum = 0.f;
    #pragma unroll
    for (int j = 0; j < 16; ++j) { v[j] = __expf(v[j] - mx); sum += v[j]; }
    #pragma unroll
    for (int m = 1; m <= 32; m <<= 1) sum += __shfl_xor(sum, m, 64);
    if ((tid & 63) == 0) red[4 + (tid >> 6)] = sum;
    __syncthreads();
    sum = red[4] + red[5] + red[6] + red[7];
    const float inv = 1.f / sum;
    float* arow = attn + (size_t)b * TT;
    #pragma unroll
    for (int j = 0; j < 16; ++j) arow[tid + 256 * j] = v[j] * inv;
}

// Kernel 3: per (b,d): mean = sum_t x*attn; var = E[x^2]-2*mean*E[x]+mean^2
__global__ void stats_kernel(const float* __restrict__ x, const float* __restrict__ attn,
                             float* __restrict__ out) {
    const int w = threadIdx.x >> 6;
    const int lane = threadIdx.x & 63;
    const int row = blockIdx.x * 4 + w;      // b*512 + d
    const int b = row >> 9;
    const int d = row & 511;
    const float* xr = x + (size_t)row * TT;
    const float* ar = attn + (size_t)b * TT;
    float sx = 0.f, sx2 = 0.f, sxw = 0.f;
    #pragma unroll 4
    for (int i = 0; i < 16; ++i) {
        int t = (i * 64 + lane) * 4;
        f32x4 xv = *reinterpret_cast<const f32x4*>(xr + t);
        f32x4 av = *reinterpret_cast<const f32x4*>(ar + t);
        #pragma unroll
        for (int j = 0; j < 4; ++j) {
            float xx = xv[j];
            sx += xx; sx2 += xx * xx; sxw += xx * av[j];
        }
    }
    #pragma unroll
    for (int m = 1; m <= 32; m <<= 1) {
        sx  += __shfl_xor(sx, m, 64);
        sx2 += __shfl_xor(sx2, m, 64);
        sxw += __shfl_xor(sxw, m, 64);
    }
    if (lane == 0) {
        const float mean = sxw;
        const float ex = sx * (1.f / TT);
        const float ex2 = sx2 * (1.f / TT);
        float var = ex2 - 2.f * mean * ex + mean * mean;
        if (var <= EPSV) var = EPSV;
        out[(size_t)b * 1024 + d] = mean;
        out[(size_t)b * 1024 + 512 + d] = sqrtf(var);
    }
}

extern "C" void kernel_launch(void* const* d_in, const int* in_sizes, int n_in,
                              void* d_out, int out_size, void* d_ws, size_t ws_size,
                              hipStream_t stream) {
    const float* x  = (const float*)d_in[0];
    const float* w1 = (const float*)d_in[1];
    const float* w2 = (const float*)d_in[2];
    float* out = (float*)d_out;

    char* ws = (char*)d_ws;
    unsigned short* w1b = (unsigned short*)ws;                    // 512*512*2 = 512 KB
    float* w2f   = (float*)(ws + DHP * DIN * 2);                  // 2 KB
    float* scores = (float*)(ws + DHP * DIN * 2 + 2048);          // 512 KB
    float* attn   = scores + NB * TT;                             // 512 KB

    prep_kernel<<<(DHP * DIN + 255) / 256, 256, 0, stream>>>(w1, w2, w1b, w2f);
    scores_kernel<<<NB * (TT / BM), 512, 0, stream>>>(x, w1b, w2f, scores);
    softmax_kernel<<<NB, 256, 0, stream>>>(scores, attn);
    stats_kernel<<<NB * DIN / 4, 256, 0, stream>>>(x, attn, out);
}

// Round 4
// 135.482 us; speedup vs baseline: 2.7839x; 1.4304x over previous
//
#include <hip/hip_runtime.h>
#include <hip/hip_bf16.h>

#define NB 32
#define DIN 512
#define TT 4096
#define DH 500
#define DHP 512
#define EPSV 1e-12f
#define BM 64
#define LDA 520  // bf16 elements; 1040B row stride, 16B-aligned rows

typedef short short8 __attribute__((ext_vector_type(8)));
typedef float f32x16 __attribute__((ext_vector_type(16)));
typedef float f32x4 __attribute__((ext_vector_type(4)));

__device__ inline unsigned short f2bf(float f) {
    unsigned int u = __builtin_bit_cast(unsigned int, f);
    unsigned int r = (u + 0x7fffu + ((u >> 16) & 1u)) >> 16;
    return (unsigned short)r;
}

// Kernel 0: pack w1 -> bf16 MFMA-fragment order [hb=16][ks=32][lane=64][8],
// so a wave's A-fragment load is 64 lanes x contiguous 16B = 1KB coalesced.
// For lane: l31=lane&31 (row in 32-panel), kh=lane>>5 (k-half).
//   h = hb*32 + l31,  d = ks*16 + kh*8 + j
__global__ void prep_kernel(const float* __restrict__ w1, const float* __restrict__ w2,
                            unsigned short* __restrict__ w1b, float* __restrict__ w2f) {
    int idx = blockIdx.x * blockDim.x + threadIdx.x;
    if (idx < DHP * DIN) {
        const int j    = idx & 7;
        const int lane = (idx >> 3) & 63;
        const int ks   = (idx >> 9) & 31;
        const int hb   = idx >> 14;
        const int h = hb * 32 + (lane & 31);
        const int d = ks * 16 + (lane >> 5) * 8 + j;
        float v = (h < DH) ? w1[h * DIN + d] : 0.f;
        w1b[idx] = f2bf(v);
        if (idx < DHP) w2f[idx] = (idx < DH) ? w2[idx] : 0.f;
    }
}

// Kernel 1: scores[b][t] = sum_h w2[h]*relu(sum_d x[b,d,t]*w1[h,d])
// Block: 8 waves, 64-t tile, all 512 h. Wave w owns h-panels {2w, 2w+1}
// (64 rows) x 2 t-tiles -> 4 f32x16 accumulators. A-operand = w1 (m=h),
// B-operand = x^T tile (n=t): D cols (lane&31)=t, rows=h, so the relu*w2
// reduction over h is in-lane. w1b is fragment-packed: coalesced 1KB loads.
__launch_bounds__(512, 4)
__global__ void scores_kernel(const float* __restrict__ x,
                              const unsigned short* __restrict__ w1b,
                              const float* __restrict__ w2f,
                              float* __restrict__ scores) {
    __shared__ unsigned short A_lds[BM][LDA];
    __shared__ float score_lds[BM];

    const int tid = threadIdx.x;
    const int b = blockIdx.x >> 6;             // TT/BM = 64 t-tiles per batch
    const int t0 = (blockIdx.x & 63) * BM;

    if (tid < BM) score_lds[tid] = 0.f;

    // ---- Stage x[b, :, t0..t0+63] -> A_lds[t][d] (bf16) ----
    {
        const int ts = tid & 63;
        const int dg = tid >> 6;               // 0..7
        const float* xb = x + (size_t)b * DIN * TT + t0 + ts;
        #pragma unroll
        for (int oct = 0; oct < 8; ++oct) {
            const int d0 = dg * 64 + oct * 8;
            short8 pk;
            #pragma unroll
            for (int j = 0; j < 8; ++j)
                pk[j] = (short)f2bf(xb[(size_t)(d0 + j) * TT]);
            *reinterpret_cast<short8*>(&A_lds[ts][d0]) = pk;
        }
    }
    __syncthreads();

    const int w = tid >> 6;                    // wave id: h-panels {2w,2w+1}
    const int lane = tid & 63;
    const int lane31 = lane & 31;
    const int khalf = lane >> 5;
    const int hrow0 = w * 64;

    f32x16 acc00, acc01, acc10, acc11;
    #pragma unroll
    for (int g = 0; g < 16; ++g) { acc00[g] = 0.f; acc01[g] = 0.f; acc10[g] = 0.f; acc11[g] = 0.f; }

    // fragment-packed w1b: panel stride = 32*64*8 = 16384 u16 (32KB)
    const unsigned short* base0 = w1b + (size_t)w * 32768 + (size_t)lane * 8;
    const unsigned short* base1 = base0 + 16384;
    const unsigned short* Bp0 = &A_lds[lane31][khalf * 8];
    const unsigned short* Bp1 = &A_lds[32 + lane31][khalf * 8];

    #pragma unroll 4
    for (int ks = 0; ks < 32; ++ks) {
        short8 a0 = *reinterpret_cast<const short8*>(base0 + ks * 512);
        short8 a1 = *reinterpret_cast<const short8*>(base1 + ks * 512);
        short8 b0 = *reinterpret_cast<const short8*>(Bp0 + ks * 16);
        short8 b1 = *reinterpret_cast<const short8*>(Bp1 + ks * 16);
        acc00 = __builtin_amdgcn_mfma_f32_32x32x16_bf16(a0, b0, acc00, 0, 0, 0);
        acc01 = __builtin_amdgcn_mfma_f32_32x32x16_bf16(a0, b1, acc01, 0, 0, 0);
        acc10 = __builtin_amdgcn_mfma_f32_32x32x16_bf16(a1, b0, acc10, 0, 0, 0);
        acc11 = __builtin_amdgcn_mfma_f32_32x32x16_bf16(a1, b1, acc11, 0, 0, 0);
    }

    // ---- in-lane reduce over h, then combine khalf halves ----
    float s0 = 0.f, s1 = 0.f;
    #pragma unroll
    for (int g = 0; g < 16; ++g) {
        const int rp = (g & 3) + 8 * (g >> 2) + 4 * khalf;
        const float w20 = w2f[hrow0 + rp];
        const float w21 = w2f[hrow0 + 32 + rp];
        s0 += fmaxf(acc00[g], 0.f) * w20 + fmaxf(acc10[g], 0.f) * w21;
        s1 += fmaxf(acc01[g], 0.f) * w20 + fmaxf(acc11[g], 0.f) * w21;
    }
    s0 += __shfl_xor(s0, 32, 64);
    s1 += __shfl_xor(s1, 32, 64);
    if (khalf == 0) {
        atomicAdd(&score_lds[lane31], s0);
        atomicAdd(&score_lds[32 + lane31], s1);
    }
    __syncthreads();
    if (tid < BM) scores[(size_t)b * TT + t0 + tid] = score_lds[tid];
}

// Kernel 2: softmax over T per batch
__global__ void softmax_kernel(const float* __restrict__ scores, float* __restrict__ attn) {
    __shared__ float red[8];
    const int b = blockIdx.x;
    const int tid = threadIdx.x;
    const float* srow = scores + (size_t)b * TT;
    float v[16];
    float mx = -1e30f;
    #pragma unroll
    for (int j = 0; j < 16; ++j) { v[j] = srow[tid + 256 * j]; mx = fmaxf(mx, v[j]); }
    #pragma unroll
    for (int m = 1; m <= 32; m <<= 1) mx = fmaxf(mx, __shfl_xor(mx, m, 64));
    if ((tid & 63) == 0) red[tid >> 6] = mx;
    __syncthreads();
    mx = fmaxf(fmaxf(red[0], red[1]), fmaxf(red[2], red[3]));
    float sum = 0.f;
    #pragma unroll
    for (int j = 0; j < 16; ++j) { v[j] = __expf(v[j] - mx); sum += v[j]; }
    #pragma unroll
    for (int m = 1; m <= 32; m <<= 1) sum += __shfl_xor(sum, m, 64);
    if ((tid & 63) == 0) red[4 + (tid >> 6)] = sum;
    __syncthreads();
    sum = red[4] + red[5] + red[6] + red[7];
    const float inv = 1.f / sum;
    float* arow = attn + (size_t)b * TT;
    #pragma unroll
    for (int j = 0; j < 16; ++j) arow[tid + 256 * j] = v[j] * inv;
}

// Kernel 3: per (b,d): mean = sum_t x*attn; var = E[x^2]-2*mean*E[x]+mean^2
__global__ void stats_kernel(const float* __restrict__ x, const float* __restrict__ attn,
                             float* __restrict__ out) {
    const int w = threadIdx.x >> 6;
    const int lane = threadIdx.x & 63;
    const int row = blockIdx.x * 4 + w;      // b*512 + d
    const int b = row >> 9;
    const int d = row & 511;
    const float* xr = x + (size_t)row * TT;
    const float* ar = attn + (size_t)b * TT;
    float sx = 0.f, sx2 = 0.f, sxw = 0.f;
    #pragma unroll 4
    for (int i = 0; i < 16; ++i) {
        int t = (i * 64 + lane) * 4;
        f32x4 xv = *reinterpret_cast<const f32x4*>(xr + t);
        f32x4 av = *reinterpret_cast<const f32x4*>(ar + t);
        #pragma unroll
        for (int j = 0; j < 4; ++j) {
            float xx = xv[j];
            sx += xx; sx2 += xx * xx; sxw += xx * av[j];
        }
    }
    #pragma unroll
    for (int m = 1; m <= 32; m <<= 1) {
        sx  += __shfl_xor(sx, m, 64);
        sx2 += __shfl_xor(sx2, m, 64);
        sxw += __shfl_xor(sxw, m, 64);
    }
    if (lane == 0) {
        const float mean = sxw;
        const float ex = sx * (1.f / TT);
        const float ex2 = sx2 * (1.f / TT);
        float var = ex2 - 2.f * mean * ex + mean * mean;
        if (var <= EPSV) var = EPSV;
        out[(size_t)b * 1024 + d] = mean;
        out[(size_t)b * 1024 + 512 + d] = sqrtf(var);
    }
}

extern "C" void kernel_launch(void* const* d_in, const int* in_sizes, int n_in,
                              void* d_out, int out_size, void* d_ws, size_t ws_size,
                              hipStream_t stream) {
    const float* x  = (const float*)d_in[0];
    const float* w1 = (const float*)d_in[1];
    const float* w2 = (const float*)d_in[2];
    float* out = (float*)d_out;

    char* ws = (char*)d_ws;
    unsigned short* w1b = (unsigned short*)ws;                    // 512*512*2 = 512 KB
    float* w2f   = (float*)(ws + DHP * DIN * 2);                  // 2 KB
    float* scores = (float*)(ws + DHP * DIN * 2 + 2048);          // 512 KB
    float* attn   = scores + NB * TT;                             // 512 KB

    prep_kernel<<<(DHP * DIN + 255) / 256, 256, 0, stream>>>(w1, w2, w1b, w2f);
    scores_kernel<<<NB * (TT / BM), 512, 0, stream>>>(x, w1b, w2f, scores);
    softmax_kernel<<<NB, 256, 0, stream>>>(scores, attn);
    stats_kernel<<<NB * DIN / 4, 256, 0, stream>>>(x, attn, out);
}

// Round 5
// 124.193 us; speedup vs baseline: 3.0369x; 1.0909x over previous
//
#include <hip/hip_runtime.h>
#include <hip/hip_bf16.h>

#define NB 32
#define DIN 512
#define TT 4096
#define DH 500
#define DHP 512
#define EPSV 1e-12f
#define BM 64
#define LDA 520  // bf16 elements; 1040B row stride, 16B-aligned rows
#define NTILES (TT / BM)   // 64 t-tiles per batch

typedef short short8 __attribute__((ext_vector_type(8)));
typedef float f32x16 __attribute__((ext_vector_type(16)));
typedef float f32x4 __attribute__((ext_vector_type(4)));

__device__ inline unsigned short f2bf(float f) {
    unsigned int u = __builtin_bit_cast(unsigned int, f);
    unsigned int r = (u + 0x7fffu + ((u >> 16) & 1u)) >> 16;
    return (unsigned short)r;
}
__device__ inline float bf2f(unsigned short h) {
    unsigned int u = ((unsigned int)h) << 16;
    return __builtin_bit_cast(float, u);
}

// Kernel 0: pack w1 -> bf16 MFMA-fragment order [hb=16][ks=32][lane=64][8]
//   h = hb*32 + (lane&31),  d = ks*16 + (lane>>5)*8 + j
__global__ void prep_kernel(const float* __restrict__ w1, const float* __restrict__ w2,
                            unsigned short* __restrict__ w1b, float* __restrict__ w2f) {
    int idx = blockIdx.x * blockDim.x + threadIdx.x;
    if (idx < DHP * DIN) {
        const int j    = idx & 7;
        const int lane = (idx >> 3) & 63;
        const int ks   = (idx >> 9) & 31;
        const int hb   = idx >> 14;
        const int h = hb * 32 + (lane & 31);
        const int d = ks * 16 + (lane >> 5) * 8 + j;
        float v = (h < DH) ? w1[h * DIN + d] : 0.f;
        w1b[idx] = f2bf(v);
        if (idx < DHP) w2f[idx] = (idx < DH) ? w2[idx] : 0.f;
    }
}

// Kernel 1 (fused): per (b, 64-t tile):
//   scores s_t  -> block-local softmax partial (m_blk, Z_blk, e_t)
//   per-d partials over the tile: sx = sum x~, sx2 = sum x~^2, swx = sum e_t*x~
// Partials go to global; a tiny combine kernel merges the 64 tiles per batch.
__launch_bounds__(512, 4)
__global__ void scores_fused(const float* __restrict__ x,
                             const unsigned short* __restrict__ w1b,
                             const float* __restrict__ w2f,
                             float* __restrict__ pm, float* __restrict__ pz,
                             float* __restrict__ pswx, float* __restrict__ psx,
                             float* __restrict__ psx2) {
    __shared__ unsigned short A_lds[BM][LDA];
    __shared__ float score_p[8][BM];
    __shared__ float w_lds[BM];

    const int tid = threadIdx.x;
    const int b = blockIdx.x >> 6;             // NTILES = 64 tiles per batch
    const int t0 = (blockIdx.x & 63) * BM;

    // ---- Phase 1: stage x[b, :, t0..t0+63] -> A_lds[t][d] (bf16) ----
    {
        const int ts = tid & 63;
        const int dg = tid >> 6;               // 0..7
        const float* xb = x + (size_t)b * DIN * TT + t0 + ts;
        #pragma unroll
        for (int oct = 0; oct < 8; ++oct) {
            const int d0 = dg * 64 + oct * 8;
            short8 pk;
            #pragma unroll
            for (int j = 0; j < 8; ++j)
                pk[j] = (short)f2bf(xb[(size_t)(d0 + j) * TT]);
            *reinterpret_cast<short8*>(&A_lds[ts][d0]) = pk;
        }
    }
    __syncthreads();

    // ---- Phase 2: MFMA. Wave w owns h-panels {2w,2w+1}; A=w1 (m=h),
    // B=x^T (n=t): D cols (lane&31)=t, rows=h -> relu*w2 reduce is in-lane.
    const int w = tid >> 6;
    const int lane = tid & 63;
    const int lane31 = lane & 31;
    const int khalf = lane >> 5;
    const int hrow0 = w * 64;

    f32x16 acc00, acc01, acc10, acc11;
    #pragma unroll
    for (int g = 0; g < 16; ++g) { acc00[g] = 0.f; acc01[g] = 0.f; acc10[g] = 0.f; acc11[g] = 0.f; }

    const unsigned short* base0 = w1b + (size_t)w * 32768 + (size_t)lane * 8;
    const unsigned short* base1 = base0 + 16384;
    const unsigned short* Bp0 = &A_lds[lane31][khalf * 8];
    const unsigned short* Bp1 = &A_lds[32 + lane31][khalf * 8];

    #pragma unroll 4
    for (int ks = 0; ks < 32; ++ks) {
        short8 a0 = *reinterpret_cast<const short8*>(base0 + ks * 512);
        short8 a1 = *reinterpret_cast<const short8*>(base1 + ks * 512);
        short8 b0 = *reinterpret_cast<const short8*>(Bp0 + ks * 16);
        short8 b1 = *reinterpret_cast<const short8*>(Bp1 + ks * 16);
        acc00 = __builtin_amdgcn_mfma_f32_32x32x16_bf16(a0, b0, acc00, 0, 0, 0);
        acc01 = __builtin_amdgcn_mfma_f32_32x32x16_bf16(a0, b1, acc01, 0, 0, 0);
        acc10 = __builtin_amdgcn_mfma_f32_32x32x16_bf16(a1, b0, acc10, 0, 0, 0);
        acc11 = __builtin_amdgcn_mfma_f32_32x32x16_bf16(a1, b1, acc11, 0, 0, 0);
    }

    float s0 = 0.f, s1 = 0.f;
    #pragma unroll
    for (int g = 0; g < 16; ++g) {
        const int rp = (g & 3) + 8 * (g >> 2) + 4 * khalf;
        const float w20 = w2f[hrow0 + rp];
        const float w21 = w2f[hrow0 + 32 + rp];
        s0 += fmaxf(acc00[g], 0.f) * w20 + fmaxf(acc10[g], 0.f) * w21;
        s1 += fmaxf(acc01[g], 0.f) * w20 + fmaxf(acc11[g], 0.f) * w21;
    }
    s0 += __shfl_xor(s0, 32, 64);
    s1 += __shfl_xor(s1, 32, 64);
    if (khalf == 0) {                          // deterministic per-wave partials
        score_p[w][lane31] = s0;
        score_p[w][32 + lane31] = s1;
    }
    __syncthreads();

    // ---- Phase 3: wave 0 finalizes scores -> e_t, m_blk, Z_blk ----
    if (tid < BM) {
        float s = 0.f;
        #pragma unroll
        for (int ww = 0; ww < 8; ++ww) s += score_p[ww][tid];
        float m = s;
        #pragma unroll
        for (int k = 1; k <= 32; k <<= 1) m = fmaxf(m, __shfl_xor(m, k, 64));
        float e = __expf(s - m);
        float Z = e;
        #pragma unroll
        for (int k = 1; k <= 32; k <<= 1) Z += __shfl_xor(Z, k, 64);
        w_lds[tid] = e;
        if (tid == 0) { pm[blockIdx.x] = m; pz[blockIdx.x] = Z; }
    }
    __syncthreads();

    // ---- Phase 4: per-d partials over the tile's 64 t ----
    {
        const int d = tid;                     // 0..511
        float sx = 0.f, sx2 = 0.f, swx = 0.f;
        #pragma unroll 8
        for (int t = 0; t < BM; ++t) {
            const float xv = bf2f(A_lds[t][d]);
            const float wv = w_lds[t];
            sx += xv; sx2 += xv * xv; swx += wv * xv;
        }
        const size_t o = (size_t)blockIdx.x * DHP + d;
        psx[o] = sx; psx2[o] = sx2; pswx[o] = swx;
    }
}

// Kernel 2: combine 64 tiles per batch -> mean, stddev
__global__ void combine_kernel(const float* __restrict__ pm, const float* __restrict__ pz,
                               const float* __restrict__ pswx, const float* __restrict__ psx,
                               const float* __restrict__ psx2, float* __restrict__ out) {
    __shared__ float sm[NTILES], sz[NTILES];
    const int b = blockIdx.x;
    const int tid = threadIdx.x;               // d = tid, 0..511
    if (tid < NTILES) { sm[tid] = pm[b * NTILES + tid]; sz[tid] = pz[b * NTILES + tid]; }
    __syncthreads();

    float mg = -1e30f;
    #pragma unroll 8
    for (int i = 0; i < NTILES; ++i) mg = fmaxf(mg, sm[i]);
    float denom = 0.f;
    #pragma unroll 8
    for (int i = 0; i < NTILES; ++i) denom += sz[i] * __expf(sm[i] - mg);

    float num = 0.f, sx = 0.f, sx2 = 0.f;
    #pragma unroll 4
    for (int i = 0; i < NTILES; ++i) {
        const size_t o = ((size_t)(b * NTILES + i)) * DHP + tid;
        const float f = __expf(sm[i] - mg);
        num += f * pswx[o];
        sx  += psx[o];
        sx2 += psx2[o];
    }
    const float mean = num / denom;
    const float ex  = sx  * (1.f / TT);
    const float ex2 = sx2 * (1.f / TT);
    float var = ex2 - 2.f * mean * ex + mean * mean;
    if (var <= EPSV) var = EPSV;
    out[(size_t)b * 1024 + tid] = mean;
    out[(size_t)b * 1024 + 512 + tid] = sqrtf(var);
}

extern "C" void kernel_launch(void* const* d_in, const int* in_sizes, int n_in,
                              void* d_out, int out_size, void* d_ws, size_t ws_size,
                              hipStream_t stream) {
    const float* x  = (const float*)d_in[0];
    const float* w1 = (const float*)d_in[1];
    const float* w2 = (const float*)d_in[2];
    float* out = (float*)d_out;

    char* ws = (char*)d_ws;
    unsigned short* w1b = (unsigned short*)ws;                    // 512 KB
    float* w2f  = (float*)(ws + 524288);                          // 2 KB
    float* pm   = (float*)(ws + 526336);                          // 8 KB
    float* pz   = (float*)(ws + 534528);                          // 8 KB
    float* pswx = (float*)(ws + 542720);                          // 4 MB
    float* psx  = pswx + (size_t)NB * NTILES * DHP;               // 4 MB
    float* psx2 = psx  + (size_t)NB * NTILES * DHP;               // 4 MB

    prep_kernel<<<(DHP * DIN + 255) / 256, 256, 0, stream>>>(w1, w2, w1b, w2f);
    scores_fused<<<NB * NTILES, 512, 0, stream>>>(x, w1b, w2f, pm, pz, pswx, psx, psx2);
    combine_kernel<<<NB, 512, 0, stream>>>(pm, pz, pswx, psx, psx2, out);
}